// Round 2
// baseline (536.283 us; speedup 1.0000x reference)
//
#include <hip/hip_runtime.h>

// OTPE single timestep on MI355X (gfx950).
// Inputs: x[8192], W[8192,4096], u[4096], E[8192,4096], R_hat[8192,4096],
//         g_bar[4096], ratio[1]  (all f32)
// Outputs (concat): s[4096], u_new[4096], E_new[8192,4096], R_new[8192,4096],
//                   g_bar_new[4096], ratio_new[1]
//
// Memory-bound: ~640 MB unavoidable HBM traffic -> ~100 us floor at 6.3 TB/s.
// R2 changes: atomic-free split-K matvec (partials reduced in finalize, no
// memset dispatch), fully-unrolled elemwise for ILP, nontemporal loads/stores
// on the streamed 128 MB arrays.

typedef float f4 __attribute__((ext_vector_type(4)));

#define SIG_TAU 0.8807970779778823f  // sigmoid(2.0) in f32

constexpr int N_IN  = 8192;
constexpr int N_OUT = 4096;
constexpr int NCG   = N_OUT / 4;          // 1024 float4 column-groups
constexpr int RPC   = 64;                 // rows per chunk
constexpr int NCHUNK = N_IN / RPC;        // 128 split-K chunks

// Output offsets (floats)
constexpr size_t OFF_S     = 0;
constexpr size_t OFF_U     = (size_t)N_OUT;
constexpr size_t OFF_E     = (size_t)2 * N_OUT;
constexpr size_t OFF_R     = OFF_E + (size_t)N_IN * N_OUT;
constexpr size_t OFF_G     = OFF_R + (size_t)N_IN * N_OUT;
constexpr size_t OFF_RATIO = OFF_G + (size_t)N_OUT;

// Split-K matvec: part[chunk][cg] = sum over 64 rows of x[i]*W[i, cg*4..cg*4+3].
// Coalesced float4 column reads; x[i] is block-uniform (scalar path). No atomics.
__global__ __launch_bounds__(256) void matvec_partial(
    const float* __restrict__ x, const f4* __restrict__ W4,
    f4* __restrict__ part) {
    const int cg   = blockIdx.x * 256 + threadIdx.x;   // 0..1023
    const int row0 = blockIdx.y * RPC;
    f4 a = {0.f, 0.f, 0.f, 0.f};
#pragma unroll 8
    for (int r = 0; r < RPC; ++r) {
        const float xv = x[row0 + r];
        const f4    w  = W4[(size_t)(row0 + r) * NCG + cg];
        a += w * xv;
    }
    part[(size_t)blockIdx.y * NCG + cg] = a;
}

// Reduce split-K partials, then spike / surrogate / soft reset / g_bar / ratio.
__global__ __launch_bounds__(256) void finalize(
    const float* __restrict__ part, const float* __restrict__ u,
    const float* __restrict__ g_bar, const float* __restrict__ ratio,
    float* __restrict__ out, float* __restrict__ sg_ws) {
    const int j = blockIdx.x * 256 + threadIdx.x;      // 0..4095
    float acc = 0.f;
#pragma unroll 8
    for (int c = 0; c < NCHUNK; ++c)
        acc += part[(size_t)c * N_OUT + j];

    const float u_pre = fmaf(SIG_TAU, u[j], acc);
    const float s     = (u_pre >= 1.0f) ? 1.0f : 0.0f;
    const float t     = 1.0f / fmaf(10.0f, fabsf(u_pre - 1.0f), 1.0f);
    const float sg    = t * t;                 // surrogate ds/du_pre
    const float u_new = u_pre - s;             // soft reset, V_TH=1

    const float r0        = SIG_TAU * ratio[0];
    const float ratio_new = r0 + 1.0f;
    const float r         = r0 / ratio_new;
    const float g_new = fmaf(r, g_bar[j], (1.0f - r) * sg);  // ds_du_prev/sig_tau == sg

    out[OFF_S + j] = s;
    out[OFF_U + j] = u_new;
    out[OFF_G + j] = g_new;
    sg_ws[j] = sg;
    if (j == 0) out[OFF_RATIO] = ratio_new;
}

// Big elementwise pass: E_new = sig_tau*E + x[i];
// R_new = sig_tau*R_hat + sg[j]*E_new.
// Exact trip count (8), fully unrolled: 16 independent 16B loads in flight.
__global__ __launch_bounds__(256) void elemwise(
    const float* __restrict__ x, const f4* __restrict__ E4,
    const f4* __restrict__ R4, const f4* __restrict__ sg4,
    f4* __restrict__ Enew4, f4* __restrict__ Rnew4) {
    const size_t base    = (size_t)blockIdx.x * 256 + threadIdx.x;
    constexpr size_t STR = (size_t)4096 * 256;         // 1,048,576 threads
#pragma unroll
    for (int k = 0; k < 8; ++k) {
        const size_t idx = base + (size_t)k * STR;
        const int i  = (int)(idx >> 10);        // row (x index), NCG=1024
        const int cg = (int)(idx & (NCG - 1));  // column group
        const float xv  = x[i];                 // wave-uniform
        const f4    sgv = sg4[cg];              // 16 KB table, cache-resident
        const f4 e  = __builtin_nontemporal_load(&E4[idx]);
        const f4 rr = __builtin_nontemporal_load(&R4[idx]);
        const f4 en = e * SIG_TAU + xv;
        const f4 rn = rr * SIG_TAU + sgv * en;
        __builtin_nontemporal_store(en, &Enew4[idx]);
        __builtin_nontemporal_store(rn, &Rnew4[idx]);
    }
}

extern "C" void kernel_launch(void* const* d_in, const int* in_sizes, int n_in,
                              void* d_out, int out_size, void* d_ws, size_t ws_size,
                              hipStream_t stream) {
    const float* x     = (const float*)d_in[0];
    const float* W     = (const float*)d_in[1];
    const float* u     = (const float*)d_in[2];
    const float* E     = (const float*)d_in[3];
    const float* R_hat = (const float*)d_in[4];
    const float* g_bar = (const float*)d_in[5];
    const float* ratio = (const float*)d_in[6];
    float* out = (float*)d_out;

    float* part = (float*)d_ws;                       // [128][4096] partials (2 MB)
    float* sg   = part + (size_t)NCHUNK * N_OUT;      // [4096] surrogate grad

    dim3 g1(NCG / 256, NCHUNK);                       // (4, 128) = 512 blocks
    matvec_partial<<<g1, 256, 0, stream>>>(x, (const f4*)W, (f4*)part);

    finalize<<<N_OUT / 256, 256, 0, stream>>>(part, u, g_bar, ratio, out, sg);

    elemwise<<<4096, 256, 0, stream>>>(
        x, (const f4*)E, (const f4*)R_hat, (const f4*)sg,
        (f4*)(out + OFF_E), (f4*)(out + OFF_R));
}